// Round 3
// baseline (425.769 us; speedup 1.0000x reference)
//
#include <hip/hip_runtime.h>

// Chamfer loss: B=8, V=4, N=2048, D=3 fp32.
// final = per_view[0] + sum_v per_view[v]; per_view = mean_b(cham_x + cham_y)
// => weight per (b,v,dir) job = ((v==0)?2:1)/8.
//
// R8: occupancy + staging rework of the R7 MFMA kernel.
//  - pack_y pre-pass: y cols packed ONCE into frag layout (16 bf16 K-slots:
//    k0-2 yh, k3-5 yl, k6-8 yh, k9-10 (wh,wl)=-0.5|y|^2 hi/lo, k11-13 yl),
//    48B padded records (conflict-free b128 reads; linear ds_write staging).
//  - main: block=4 waves/128 rows; wave pair splits col-tiles by parity
//    (B-frag reuse=2 kept) -> 4096 waves = 4/SIMD, 4 blocks/CU.
//  - chunk=256 cols double-buffered (2x12KB), reg-staged (T14: load early,
//    ds_write late), ONE __syncthreads per chunk.
//  - tail: in-reg butterfly row-max, cross-wave merge via LDS, block sum.

#define B_ 8
#define V_ 4
#define N_ 2048
#define JOBS 64
#define RPB 128                        // rows per block
#define GRID_ (JOBS * (N_ / RPB))      // 1024 blocks = 4/CU
#define CHUNK 256                      // cols per LDS chunk
#define NCHUNK (N_ / CHUNK)            // 8
#define CPITCH 24                      // ushorts per packed col (48 B)
#define CHV (CHUNK * CPITCH / 8)       // float4 units per chunk = 768

typedef short bf16x8 __attribute__((ext_vector_type(8)));
typedef float f32x16 __attribute__((ext_vector_type(16)));

__device__ __forceinline__ unsigned short f2bf(float f) {
  union { float f; unsigned u; } v; v.f = f;
  const unsigned r = v.u + 0x7fffu + ((v.u >> 16) & 1u);  // RNE
  return (unsigned short)(r >> 16);
}
__device__ __forceinline__ float bf2f(unsigned short h) {
  union { unsigned u; float f; } v; v.u = ((unsigned)h) << 16;
  return v.f;
}

__device__ __forceinline__ void pack_col(float y0, float y1, float y2,
                                         unsigned short* dst) {
  const unsigned short h0 = f2bf(y0), h1 = f2bf(y1), h2 = f2bf(y2);
  const unsigned short l0 = f2bf(y0 - bf2f(h0));
  const unsigned short l1 = f2bf(y1 - bf2f(h1));
  const unsigned short l2 = f2bf(y2 - bf2f(h2));
  const float w = -0.5f * fmaf(y0, y0, fmaf(y1, y1, y2 * y2));
  const unsigned short wh = f2bf(w);
  const unsigned short wl = f2bf(w - bf2f(wh));
  bf16x8 b0, b1;
  b0[0] = (short)h0; b0[1] = (short)h1; b0[2] = (short)h2;   // k0-2
  b0[3] = (short)l0; b0[4] = (short)l1; b0[5] = (short)l2;   // k3-5
  b0[6] = (short)h0; b0[7] = (short)h1;                      // k6-7
  b1[0] = (short)h2;                                         // k8
  b1[1] = (short)wh; b1[2] = (short)wl;                      // k9-10
  b1[3] = (short)l0; b1[4] = (short)l1; b1[5] = (short)l2;   // k11-13
  b1[6] = 0; b1[7] = 0;                                      // k14-15
  *(bf16x8*)(dst) = b0;
  *(bf16x8*)(dst + 8) = b1;
}

// Pack all 64 (pair, src) y-panels: panel even = X data, odd = T data.
// Record layout [panel][col][24 ushorts] == linear tid*24.
__global__ __launch_bounds__(256) void pack_y(
    const float* __restrict__ X, const float* __restrict__ T,
    unsigned short* __restrict__ P) {
  const int tid = blockIdx.x * 256 + threadIdx.x;   // [0, 131072)
  const int panel = tid >> 11;
  const int col = tid & (N_ - 1);
  const int pair = panel >> 1;
  const float* src = ((panel & 1) ? T : X) + (size_t)pair * N_ * 3 + col * 3;
  pack_col(src[0], src[1], src[2], P + (size_t)tid * CPITCH);
}

__global__ __launch_bounds__(256, 4) void chamfer_main(
    const float* __restrict__ X, const float* __restrict__ T,
    const unsigned short* __restrict__ P, float* __restrict__ bsum) {
  __shared__ unsigned short yf[2][CHUNK * CPITCH];  // 2 x 12 KB
  __shared__ float redrow[4][64];
  __shared__ float redxn[2][64];
  __shared__ float red4[4];

  // XCD swizzle: physical p -> XCD p&7; XCD x owns 128 logical bids = 8 jobs.
  const int p = blockIdx.x;
  const int bid = (p & 7) * (GRID_ / 8) + (p >> 3);
  const int job = bid >> 4;          // [0,64): 16 blocks per job
  const int rc  = bid & 15;          // row-chunk of 128
  const int pair = job >> 1;
  const int dir  = job & 1;          // 0: rows=X cols=T (cham_x), 1: swapped
  const float* xb = (dir ? T : X) + (size_t)pair * N_ * 3;
  const unsigned short* Pb =
      P + ((size_t)((pair << 1) | (dir ^ 1))) * N_ * CPITCH;  // y frag panel
  const int t = threadIdx.x;
  const int lane = t & 63;
  const int wv = t >> 6;
  const int lr = lane & 31;          // A-row / B-col within tile
  const int g  = lane >> 5;          // K-group
  const int rowhalf = wv >> 1;       // which 64-row half of the block
  const int parity  = wv & 1;        // which col-tile parity this wave owns

  // ---- A fragments: 2 row-tiles of 32 (shared by the wave pair) ----
  bf16x8 afrag[2];
  float xn2[2];
  const int rbase = rc * RPB + rowhalf * 64;
#pragma unroll
  for (int rt = 0; rt < 2; ++rt) {
    const int r = rbase + rt * 32 + lr;
    const float x0 = xb[r * 3 + 0], x1 = xb[r * 3 + 1], x2 = xb[r * 3 + 2];
    xn2[rt] = fmaf(x0, x0, fmaf(x1, x1, x2 * x2));
    const unsigned short h0 = f2bf(x0), h1 = f2bf(x1), h2 = f2bf(x2);
    const unsigned short l0 = f2bf(x0 - bf2f(h0));
    const unsigned short l1 = f2bf(x1 - bf2f(h1));
    const unsigned short l2 = f2bf(x2 - bf2f(h2));
    const unsigned short ONE = 0x3F80;  // bf16 1.0
    bf16x8 a;
    if (g == 0) {
      a[0] = (short)h0; a[1] = (short)h1; a[2] = (short)h2;
      a[3] = (short)h0; a[4] = (short)h1; a[5] = (short)h2;
      a[6] = (short)l0; a[7] = (short)l1;
    } else {
      a[0] = (short)l2; a[1] = (short)ONE; a[2] = (short)ONE;
      a[3] = (short)l0; a[4] = (short)l1; a[5] = (short)l2;
      a[6] = 0; a[7] = 0;
    }
    afrag[rt] = a;
  }

  f32x16 r0, r1;
#pragma unroll
  for (int j = 0; j < 16; ++j) { r0[j] = -1e30f; r1[j] = -1e30f; }

  // ---- stage chunk 0 (all 4 waves, linear, conflict-free) ----
  const float4* Pv = (const float4*)Pb;
  {
    float4* dst = (float4*)yf[0];
    dst[t] = Pv[t]; dst[t + 256] = Pv[t + 256]; dst[t + 512] = Pv[t + 512];
  }
  __syncthreads();

#pragma unroll 2
  for (int ch = 0; ch < NCHUNK; ++ch) {
    float4 s0, s1, s2;
    if (ch + 1 < NCHUNK) {           // T14: issue next-chunk loads early
      const float4* src = Pv + (ch + 1) * CHV;
      s0 = src[t]; s1 = src[t + 256]; s2 = src[t + 512];
    }
    const unsigned short* bufb = yf[ch & 1];
    // my col-tiles this chunk: {parity, parity+2, parity+4, parity+6}
#pragma unroll
    for (int pp = 0; pp < 2; ++pp) {
      const unsigned short* pa =
          bufb + (size_t)((pp * 4 + parity) * 32 + lr) * CPITCH + g * 8;
      const bf16x8 bA = *(const bf16x8*)pa;                   // ds_read_b128
      const bf16x8 bB = *(const bf16x8*)(pa + 2 * 32 * CPITCH);
      const f32x16 d00 =
          __builtin_amdgcn_mfma_f32_32x32x16_bf16(afrag[0], bA, (f32x16){}, 0, 0, 0);
      const f32x16 d01 =
          __builtin_amdgcn_mfma_f32_32x32x16_bf16(afrag[0], bB, (f32x16){}, 0, 0, 0);
#pragma unroll
      for (int j = 0; j < 16; ++j) r0[j] = fmaxf(fmaxf(r0[j], d00[j]), d01[j]);
      const f32x16 d10 =
          __builtin_amdgcn_mfma_f32_32x32x16_bf16(afrag[1], bA, (f32x16){}, 0, 0, 0);
      const f32x16 d11 =
          __builtin_amdgcn_mfma_f32_32x32x16_bf16(afrag[1], bB, (f32x16){}, 0, 0, 0);
#pragma unroll
      for (int j = 0; j < 16; ++j) r1[j] = fmaxf(fmaxf(r1[j], d10[j]), d11[j]);
    }
    if (ch + 1 < NCHUNK) {           // write-late into the other buffer
      float4* dst = (float4*)yf[(ch + 1) & 1];
      dst[t] = s0; dst[t + 256] = s1; dst[t + 512] = s2;
    }
    __syncthreads();
  }

  // ---- tail: butterfly row-max (this wave's parity cols), cross-wave merge.
  // C layout: col=lane&31, row=(j&3)+8*(j>>2)+4*(lane>>5).
#pragma unroll
  for (int rt = 0; rt < 2; ++rt) {
#pragma unroll
    for (int j = 0; j < 16; ++j) {
      float m = rt ? r1[j] : r0[j];
      m = fmaxf(m, __shfl_xor(m, 1, 64));
      m = fmaxf(m, __shfl_xor(m, 2, 64));
      m = fmaxf(m, __shfl_xor(m, 4, 64));
      m = fmaxf(m, __shfl_xor(m, 8, 64));
      m = fmaxf(m, __shfl_xor(m, 16, 64));   // allreduce over 32 lr-lanes
      const int rl = (j & 3) + 8 * (j >> 2) + 4 * g;
      if (lr == rl) {
        redrow[wv][rt * 32 + rl] = m;
        if (!parity) redxn[rowhalf][rt * 32 + rl] = xn2[rt];
      }
    }
  }
  __syncthreads();

  float d = 0.0f;
  if (t < 128) {                      // one thread per row of the block
    const int wp = t >> 6, q = t & 63;
    const float mx = fmaxf(redrow[2 * wp][q], redrow[2 * wp + 1][q]);
    d = fmaf(-2.0f, mx, redxn[wp][q]);
  }
  const int v_ = pair & (V_ - 1);
  float acc = d * (((v_ == 0) ? 2.0f : 1.0f) * (1.0f / (float)B_));
#pragma unroll
  for (int o = 32; o > 0; o >>= 1) acc += __shfl_down(acc, o, 64);
  if (lane == 0) red4[wv] = acc;
  __syncthreads();
  if (t == 0) bsum[bid] = (red4[0] + red4[1]) + (red4[2] + red4[3]);
}

__global__ __launch_bounds__(256) void chamfer_final(
    const float* __restrict__ bsum, float* __restrict__ out) {
  __shared__ float red4[4];
  const int t = threadIdx.x;
  float v = (bsum[t] + bsum[t + 256]) + (bsum[t + 512] + bsum[t + 768]);
#pragma unroll
  for (int o = 32; o > 0; o >>= 1) v += __shfl_down(v, o, 64);
  const int lane = t & 63, wid = t >> 6;
  if (lane == 0) red4[wid] = v;
  __syncthreads();
  if (t == 0) out[0] = (red4[0] + red4[1]) + (red4[2] + red4[3]);
}

extern "C" void kernel_launch(void* const* d_in, const int* in_sizes, int n_in,
                              void* d_out, int out_size, void* d_ws, size_t ws_size,
                              hipStream_t stream) {
  const float* X = (const float*)d_in[0];
  const float* T = (const float*)d_in[1];
  float* out = (float*)d_out;
  unsigned short* P = (unsigned short*)d_ws;            // 64*2048*48B = 6 MB
  float* bsum = (float*)((char*)d_ws + (size_t)JOBS * N_ * CPITCH * 2);  // 1024 f

  pack_y<<<(JOBS * N_) / 256, 256, 0, stream>>>(X, T, P);
  chamfer_main<<<GRID_, 256, 0, stream>>>(X, T, P, bsum);
  chamfer_final<<<1, 256, 0, stream>>>(bsum, out);
}

// Round 4
// 38.149 us; speedup vs baseline: 11.1607x; 11.1607x over previous
//
#include <hip/hip_runtime.h>

// Chamfer loss: B=8, V=4, N=2048, D=3 fp32.
// final = per_view[0] + sum_v per_view[v]; per_view = mean_b(cham_x + cham_y)
// => weight per (b,v,dir) job = ((v==0)?2:1)/8.
//
// R9 = R8 structure, de-spilled (R8's launch_bounds(256,4) cap caused 1.4GB
// of scratch traffic, 425us):
//  - pack_y pre-pass: y cols packed ONCE into frag layout (16 bf16 K-slots:
//    k0-2 yh, k3-5 yl, k6-8 yh, k9-10 (wh,wl)=-0.5|y|^2 hi/lo, k11-13 yl),
//    48B records. LDS image of a chunk is a LINEAR copy of the packed panel
//    -> staging via global_load_lds width=16 (3 inst/thread, 0 staging VGPRs).
//  - main: block=4 waves/128 rows; wave pair splits col-tiles by parity
//    (B-frag reuse=2 kept) -> 4096 waves total.
//  - launch_bounds(256,3): no hard 128 cap (that's what spilled); natural
//    VGPR ~100-120 should give 4 blocks/CU anyway.
//  - chunk=256 cols double-buffered (2x12KB), ONE __syncthreads per chunk.

#define B_ 8
#define V_ 4
#define N_ 2048
#define JOBS 64
#define RPB 128                        // rows per block
#define GRID_ (JOBS * (N_ / RPB))      // 1024 blocks
#define CHUNK 256                      // cols per LDS chunk
#define NCHUNK (N_ / CHUNK)            // 8
#define CPITCH 24                      // ushorts per packed col (48 B)
#define CHBYTES (CHUNK * CPITCH * 2)   // 12288 B per chunk

typedef short bf16x8 __attribute__((ext_vector_type(8)));
typedef float f32x16 __attribute__((ext_vector_type(16)));

__device__ __forceinline__ unsigned short f2bf(float f) {
  union { float f; unsigned u; } v; v.f = f;
  const unsigned r = v.u + 0x7fffu + ((v.u >> 16) & 1u);  // RNE
  return (unsigned short)(r >> 16);
}
__device__ __forceinline__ float bf2f(unsigned short h) {
  union { unsigned u; float f; } v; v.u = ((unsigned)h) << 16;
  return v.f;
}

__device__ __forceinline__ void pack_col(float y0, float y1, float y2,
                                         unsigned short* dst) {
  const unsigned short h0 = f2bf(y0), h1 = f2bf(y1), h2 = f2bf(y2);
  const unsigned short l0 = f2bf(y0 - bf2f(h0));
  const unsigned short l1 = f2bf(y1 - bf2f(h1));
  const unsigned short l2 = f2bf(y2 - bf2f(h2));
  const float w = -0.5f * fmaf(y0, y0, fmaf(y1, y1, y2 * y2));
  const unsigned short wh = f2bf(w);
  const unsigned short wl = f2bf(w - bf2f(wh));
  bf16x8 b0, b1;
  b0[0] = (short)h0; b0[1] = (short)h1; b0[2] = (short)h2;   // k0-2
  b0[3] = (short)l0; b0[4] = (short)l1; b0[5] = (short)l2;   // k3-5
  b0[6] = (short)h0; b0[7] = (short)h1;                      // k6-7
  b1[0] = (short)h2;                                         // k8
  b1[1] = (short)wh; b1[2] = (short)wl;                      // k9-10
  b1[3] = (short)l0; b1[4] = (short)l1; b1[5] = (short)l2;   // k11-13
  b1[6] = 0; b1[7] = 0;                                      // k14-15
  *(bf16x8*)(dst) = b0;
  *(bf16x8*)(dst + 8) = b1;
}

// Pack all 64 (pair, src) y-panels: panel even = X data, odd = T data.
__global__ __launch_bounds__(256) void pack_y(
    const float* __restrict__ X, const float* __restrict__ T,
    unsigned short* __restrict__ P) {
  const int tid = blockIdx.x * 256 + threadIdx.x;   // [0, 131072)
  const int panel = tid >> 11;
  const int col = tid & (N_ - 1);
  const int pair = panel >> 1;
  const float* src = ((panel & 1) ? T : X) + (size_t)pair * N_ * 3 + col * 3;
  pack_col(src[0], src[1], src[2], P + (size_t)tid * CPITCH);
}

// Async-stage one 12KB chunk: 4 waves x 3 global_load_lds_dwordx4 (1KB/wave
// per inst). LDS dest = wave-uniform base + lane*16 (HW); global src per-lane.
__device__ __forceinline__ void stage_chunk_async(
    const unsigned short* __restrict__ Pb, unsigned short* __restrict__ buf,
    int ch, int wv, int lane) {
  const char* g = (const char*)Pb + (size_t)ch * CHBYTES + wv * 3072 + lane * 16;
  char* l = (char*)buf + wv * 3072;
#pragma unroll
  for (int i = 0; i < 3; ++i) {
    __builtin_amdgcn_global_load_lds(
        (const __attribute__((address_space(1))) unsigned int*)(g + i * 1024),
        (__attribute__((address_space(3))) unsigned int*)(l + i * 1024),
        16, 0, 0);
  }
}

__global__ __launch_bounds__(256, 3) void chamfer_main(
    const float* __restrict__ X, const float* __restrict__ T,
    const unsigned short* __restrict__ P, float* __restrict__ bsum) {
  __shared__ unsigned short yf[2][CHUNK * CPITCH];  // 2 x 12 KB
  __shared__ float redrow[4][64];
  __shared__ float redxn[2][64];
  __shared__ float red4[4];

  // XCD swizzle: physical p -> XCD p&7; XCD x owns 128 logical bids = 8 jobs.
  const int p = blockIdx.x;
  const int bid = (p & 7) * (GRID_ / 8) + (p >> 3);
  const int job = bid >> 4;          // [0,64): 16 blocks per job
  const int rc  = bid & 15;          // row-chunk of 128
  const int pair = job >> 1;
  const int dir  = job & 1;          // 0: rows=X cols=T (cham_x), 1: swapped
  const float* xb = (dir ? T : X) + (size_t)pair * N_ * 3;
  const unsigned short* Pb =
      P + ((size_t)((pair << 1) | (dir ^ 1))) * N_ * CPITCH;  // y frag panel
  const int t = threadIdx.x;
  const int lane = t & 63;
  const int wv = t >> 6;
  const int lr = lane & 31;          // A-row / B-col within tile
  const int g  = lane >> 5;          // K-group
  const int rowhalf = wv >> 1;       // which 64-row half of the block
  const int parity  = wv & 1;        // which col-tile parity this wave owns

  // ---- A fragments: 2 row-tiles of 32 (shared by the wave pair) ----
  bf16x8 afrag[2];
  float xn2[2];
  const int rbase = rc * RPB + rowhalf * 64;
#pragma unroll
  for (int rt = 0; rt < 2; ++rt) {
    const int r = rbase + rt * 32 + lr;
    const float x0 = xb[r * 3 + 0], x1 = xb[r * 3 + 1], x2 = xb[r * 3 + 2];
    xn2[rt] = fmaf(x0, x0, fmaf(x1, x1, x2 * x2));
    const unsigned short h0 = f2bf(x0), h1 = f2bf(x1), h2 = f2bf(x2);
    const unsigned short l0 = f2bf(x0 - bf2f(h0));
    const unsigned short l1 = f2bf(x1 - bf2f(h1));
    const unsigned short l2 = f2bf(x2 - bf2f(h2));
    const unsigned short ONE = 0x3F80;  // bf16 1.0
    bf16x8 a;
    if (g == 0) {
      a[0] = (short)h0; a[1] = (short)h1; a[2] = (short)h2;
      a[3] = (short)h0; a[4] = (short)h1; a[5] = (short)h2;
      a[6] = (short)l0; a[7] = (short)l1;
    } else {
      a[0] = (short)l2; a[1] = (short)ONE; a[2] = (short)ONE;
      a[3] = (short)l0; a[4] = (short)l1; a[5] = (short)l2;
      a[6] = 0; a[7] = 0;
    }
    afrag[rt] = a;
  }

  f32x16 r0, r1;
#pragma unroll
  for (int j = 0; j < 16; ++j) { r0[j] = -1e30f; r1[j] = -1e30f; }

  stage_chunk_async(Pb, yf[0], 0, wv, lane);
  __syncthreads();  // drains vmcnt(0): chunk 0 resident

  for (int ch = 0; ch < NCHUNK; ++ch) {
    if (ch + 1 < NCHUNK)  // issue next-chunk DMA early; drained by barrier
      stage_chunk_async(Pb, yf[(ch + 1) & 1], ch + 1, wv, lane);
    const unsigned short* bufb = yf[ch & 1];
    // my col-tiles this chunk: {parity, parity+2, parity+4, parity+6} (x32 cols)
#pragma unroll
    for (int pp = 0; pp < 2; ++pp) {
      const unsigned short* pa =
          bufb + (size_t)((pp * 4 + parity) * 32 + lr) * CPITCH + g * 8;
      const bf16x8 bA = *(const bf16x8*)pa;                   // ds_read_b128
      const bf16x8 bB = *(const bf16x8*)(pa + 2 * 32 * CPITCH);
      const f32x16 d00 =
          __builtin_amdgcn_mfma_f32_32x32x16_bf16(afrag[0], bA, (f32x16){}, 0, 0, 0);
      const f32x16 d01 =
          __builtin_amdgcn_mfma_f32_32x32x16_bf16(afrag[0], bB, (f32x16){}, 0, 0, 0);
#pragma unroll
      for (int j = 0; j < 16; ++j) r0[j] = fmaxf(fmaxf(r0[j], d00[j]), d01[j]);
      const f32x16 d10 =
          __builtin_amdgcn_mfma_f32_32x32x16_bf16(afrag[1], bA, (f32x16){}, 0, 0, 0);
      const f32x16 d11 =
          __builtin_amdgcn_mfma_f32_32x32x16_bf16(afrag[1], bB, (f32x16){}, 0, 0, 0);
#pragma unroll
      for (int j = 0; j < 16; ++j) r1[j] = fmaxf(fmaxf(r1[j], d10[j]), d11[j]);
    }
    __syncthreads();  // next buffer resident; current reads done before overwrite
  }

  // ---- tail: butterfly row-max (this wave's parity cols), cross-wave merge.
  // C layout: col=lane&31, row=(j&3)+8*(j>>2)+4*(lane>>5).
#pragma unroll
  for (int rt = 0; rt < 2; ++rt) {
#pragma unroll
    for (int j = 0; j < 16; ++j) {
      float m = rt ? r1[j] : r0[j];
      m = fmaxf(m, __shfl_xor(m, 1, 64));
      m = fmaxf(m, __shfl_xor(m, 2, 64));
      m = fmaxf(m, __shfl_xor(m, 4, 64));
      m = fmaxf(m, __shfl_xor(m, 8, 64));
      m = fmaxf(m, __shfl_xor(m, 16, 64));   // allreduce over 32 lr-lanes
      const int rl = (j & 3) + 8 * (j >> 2) + 4 * g;
      if (lr == rl) {
        redrow[wv][rt * 32 + rl] = m;
        if (!parity) redxn[rowhalf][rt * 32 + rl] = xn2[rt];
      }
    }
  }
  __syncthreads();

  float d = 0.0f;
  if (t < 128) {                      // one thread per row of the block
    const int wp = t >> 6, q = t & 63;
    const float mx = fmaxf(redrow[2 * wp][q], redrow[2 * wp + 1][q]);
    d = fmaf(-2.0f, mx, redxn[wp][q]);
  }
  const int v_ = pair & (V_ - 1);
  float acc = d * (((v_ == 0) ? 2.0f : 1.0f) * (1.0f / (float)B_));
#pragma unroll
  for (int o = 32; o > 0; o >>= 1) acc += __shfl_down(acc, o, 64);
  if (lane == 0) red4[wv] = acc;
  __syncthreads();
  if (t == 0) bsum[bid] = (red4[0] + red4[1]) + (red4[2] + red4[3]);
}

__global__ __launch_bounds__(256) void chamfer_final(
    const float* __restrict__ bsum, float* __restrict__ out) {
  __shared__ float red4[4];
  const int t = threadIdx.x;
  float v = (bsum[t] + bsum[t + 256]) + (bsum[t + 512] + bsum[t + 768]);
#pragma unroll
  for (int o = 32; o > 0; o >>= 1) v += __shfl_down(v, o, 64);
  const int lane = t & 63, wid = t >> 6;
  if (lane == 0) red4[wid] = v;
  __syncthreads();
  if (t == 0) out[0] = (red4[0] + red4[1]) + (red4[2] + red4[3]);
}

extern "C" void kernel_launch(void* const* d_in, const int* in_sizes, int n_in,
                              void* d_out, int out_size, void* d_ws, size_t ws_size,
                              hipStream_t stream) {
  const float* X = (const float*)d_in[0];
  const float* T = (const float*)d_in[1];
  float* out = (float*)d_out;
  unsigned short* P = (unsigned short*)d_ws;            // 64*2048*48B = 6 MB
  float* bsum = (float*)((char*)d_ws + (size_t)JOBS * N_ * CPITCH * 2);  // 1024 f

  pack_y<<<(JOBS * N_) / 256, 256, 0, stream>>>(X, T, P);
  chamfer_main<<<GRID_, 256, 0, stream>>>(X, T, P, bsum);
  chamfer_final<<<1, 256, 0, stream>>>(bsum, out);
}